// Round 16
// baseline (260.235 us; speedup 1.0000x reference)
//
#include <hip/hip_runtime.h>
#include <hip/hip_bf16.h>
#include <math.h>

#define N_NODES 50000
#define N_EDGES 25000
#define NNZ     600000
#define D       128
#define H       256

#define BW    98            // bucket width (segments per bucket)
#define NBE   256           // ceil(25000/98)
#define NBV   511           // ceil(50000/98)
#define CAPE  3072          // per-bucket record capacity, E (mean 2352, sd 48)
#define CAPV  1536          // per-bucket record capacity, V (mean 1176, sd 34)
#define CHUNK 4096          // COO items per block in place

typedef short short8 __attribute__((ext_vector_type(8)));
typedef float floatx4 __attribute__((ext_vector_type(4)));

__device__ inline ushort f2bf(float f) {              // RNE fp32 -> bf16
    uint u = __float_as_uint(f);
    u += 0x7FFF + ((u >> 16) & 1);
    return (ushort)(u >> 16);
}
__device__ inline float bflo(uint u) { return __uint_as_float(u << 16); }
__device__ inline float bfhi(uint u) { return __uint_as_float(u & 0xffff0000u); }

// ---------------------------------------------------------------- convert + CSR place (one dispatch)
__global__ void convert_and_place(const float* __restrict__ W1, ushort* __restrict__ W1b,
                                  const float* __restrict__ W2, ushort* __restrict__ W2b,
                                  const float* __restrict__ Wu, ushort* __restrict__ Wub,
                                  const int* __restrict__ v_idx, const int* __restrict__ e_idx,
                                  int* __restrict__ cntE, int* __restrict__ cntV,
                                  int2* __restrict__ recE, int2* __restrict__ recV,
                                  int convBlocks) {
    if ((int)blockIdx.x < convBlocks) {
        const int n1 = H * D / 4;
        const int n2 = D * H / 4;
        const int nu = D * D / 4;
        int j = blockIdx.x * 256 + threadIdx.x;
        const float* src; ushort* dst;
        if (j < n1)                { src = W1; dst = W1b; }
        else if ((j -= n1) < n2)   { src = W2; dst = W2b; }
        else if ((j -= n2) < nu)   { src = Wu; dst = Wub; }
        else return;
        float4 v = ((const float4*)src)[j];
        ushort4 o;
        o.x = f2bf(v.x); o.y = f2bf(v.y); o.z = f2bf(v.z); o.w = f2bf(v.w);
        ((ushort4*)dst)[j] = o;
        return;
    }

    __shared__ int hE[NBE], hV[NBV];
    __shared__ int rE[NBE], rV[NBV];
    for (int i = threadIdx.x; i < NBE; i += 256) hE[i] = 0;
    for (int i = threadIdx.x; i < NBV; i += 256) hV[i] = 0;
    __syncthreads();
    int base = (blockIdx.x - convBlocks) * CHUNK;
    int end  = min(base + CHUNK, NNZ);
    int myE[16], myV[16];
    #pragma unroll
    for (int j = 0; j < 16; ++j) {
        int i = base + threadIdx.x + j * 256;
        myE[j] = -1; myV[j] = -1;
        if (i < end) {
            myE[j] = e_idx[i];
            myV[j] = v_idx[i];
            atomicAdd(&hE[myE[j] / BW], 1);
            atomicAdd(&hV[myV[j] / BW], 1);
        }
    }
    __syncthreads();
    for (int i = threadIdx.x; i < NBE; i += 256) {
        int c = hE[i];
        rE[i] = c ? atomicAdd(&cntE[i], c) : 0;
    }
    for (int i = threadIdx.x; i < NBV; i += 256) {
        int c = hV[i];
        rV[i] = c ? atomicAdd(&cntV[i], c) : 0;
    }
    __syncthreads();
    for (int i = threadIdx.x; i < NBE; i += 256) hE[i] = 0;
    for (int i = threadIdx.x; i < NBV; i += 256) hV[i] = 0;
    __syncthreads();
    #pragma unroll
    for (int j = 0; j < 16; ++j) {
        if (myE[j] >= 0) {
            int bk = myE[j] / BW;
            int p = rE[bk] + atomicAdd(&hE[bk], 1);
            recE[(size_t)bk * CAPE + p] = make_int2(myE[j], myV[j]);
            bk = myV[j] / BW;
            p = rV[bk] + atomicAdd(&hV[bk], 1);
            recV[(size_t)bk * CAPV + p] = make_int2(myV[j], myE[j]);
        }
    }
}

// one block per bucket -> per-segment {start,count} descriptors + recip + adjacency
__global__ void bucket_final(const int2* __restrict__ recE, const int* __restrict__ cntE,
                             const int2* __restrict__ recV, const int* __restrict__ cntV,
                             int2* __restrict__ e_sd, float* __restrict__ erecip, int* __restrict__ e_vert,
                             int2* __restrict__ v_sd, float* __restrict__ vrecip, int* __restrict__ v_edge) {
    __shared__ int hist[BW], scn[BW], cur[BW];
    const bool eSide = blockIdx.x < NBE;
    const int b = eSide ? blockIdx.x : blockIdx.x - NBE;
    const int cap   = eSide ? CAPE : CAPV;
    const int2* rec = (eSide ? recE : recV) + (size_t)b * cap;
    const int cnt   = (eSide ? cntE : cntV)[b];
    const int nseg  = eSide ? N_EDGES : N_NODES;
    int2* sd        = eSide ? e_sd : v_sd;
    float* recip    = eSide ? erecip : vrecip;
    int* outv       = (eSide ? e_vert : v_edge) + (size_t)b * cap;
    const int k0 = b * BW;

    for (int i = threadIdx.x; i < BW; i += 256) hist[i] = 0;
    __syncthreads();
    for (int i = threadIdx.x; i < cnt; i += 256)
        atomicAdd(&hist[rec[i].x - k0], 1);
    __syncthreads();

    if (threadIdx.x < 64) {
        int lane = threadIdx.x;
        int v0 = hist[lane];
        int a = v0;
        #pragma unroll
        for (int d = 1; d < 64; d <<= 1) {
            int u = __shfl_up(a, d, 64);
            if (lane >= d) a += u;
        }
        scn[lane] = a - v0;
        int tot0 = __shfl(a, 63, 64);
        int v1 = (lane < BW - 64) ? hist[64 + lane] : 0;
        int a1 = v1;
        #pragma unroll
        for (int d = 1; d < 64; d <<= 1) {
            int u = __shfl_up(a1, d, 64);
            if (lane >= d) a1 += u;
        }
        if (lane < BW - 64) scn[64 + lane] = tot0 + a1 - v1;
    }
    __syncthreads();

    const int gbase = b * cap;
    for (int i = threadIdx.x; i < BW; i += 256) {
        int seg = k0 + i;
        if (seg < nseg) {
            sd[seg] = make_int2(gbase + scn[i], hist[i]);
            recip[seg] = 1.0f / (float)max(hist[i], 1);
        }
        cur[i] = scn[i];
    }
    __syncthreads();
    for (int i = threadIdx.x; i < cnt; i += 256) {
        int2 r = rec[i];
        int p = atomicAdd(&cur[r.x - k0], 1);
        outv[p] = r.y;
    }
}

// ---------------------------------------------------------------- gather (one segment per 16-lane quarter)
// Direct index loads; 8-row rounds -> 8 row loads in flight per quarter.
__global__ void gather_rows(const ushort* __restrict__ src,
                            const int2* __restrict__ sd,
                            const int* __restrict__ list,
                            const float* __restrict__ recip,
                            const ushort* __restrict__ uadd,
                            ushort* __restrict__ outbuf,
                            const float* __restrict__ Wa,
                            const float* __restrict__ ba,
                            float* __restrict__ headout,
                            int nseg) {
    long long gtid = (long long)blockIdx.x * blockDim.x + threadIdx.x;
    int seg = (int)(gtid >> 4);           // one segment per 16 lanes
    int ql  = threadIdx.x & 15;           // feature group: 8 features at ql*8
    if (seg >= nseg) return;
    int2 dsc = sd[seg];
    int s = dsc.x, cnt = dsc.y;
    const ushort* sp = src + ql * 8;

    float f0 = 0.f, f1 = 0.f, f2 = 0.f, f3 = 0.f;
    float f4 = 0.f, f5 = 0.f, f6 = 0.f, f7 = 0.f;

    int p = 0;
    for (; p + 8 <= cnt; p += 8) {
        int r0 = list[s + p + 0];
        int r1 = list[s + p + 1];
        int r2 = list[s + p + 2];
        int r3 = list[s + p + 3];
        int r4 = list[s + p + 4];
        int r5 = list[s + p + 5];
        int r6 = list[s + p + 6];
        int r7 = list[s + p + 7];
        uint4 t0 = *(const uint4*)(sp + (size_t)r0 * D);
        uint4 t1 = *(const uint4*)(sp + (size_t)r1 * D);
        uint4 t2 = *(const uint4*)(sp + (size_t)r2 * D);
        uint4 t3 = *(const uint4*)(sp + (size_t)r3 * D);
        uint4 t4 = *(const uint4*)(sp + (size_t)r4 * D);
        uint4 t5 = *(const uint4*)(sp + (size_t)r5 * D);
        uint4 t6 = *(const uint4*)(sp + (size_t)r6 * D);
        uint4 t7 = *(const uint4*)(sp + (size_t)r7 * D);
        f0 += bflo(t0.x)+bflo(t1.x)+bflo(t2.x)+bflo(t3.x)
            + bflo(t4.x)+bflo(t5.x)+bflo(t6.x)+bflo(t7.x);
        f1 += bfhi(t0.x)+bfhi(t1.x)+bfhi(t2.x)+bfhi(t3.x)
            + bfhi(t4.x)+bfhi(t5.x)+bfhi(t6.x)+bfhi(t7.x);
        f2 += bflo(t0.y)+bflo(t1.y)+bflo(t2.y)+bflo(t3.y)
            + bflo(t4.y)+bflo(t5.y)+bflo(t6.y)+bflo(t7.y);
        f3 += bfhi(t0.y)+bfhi(t1.y)+bfhi(t2.y)+bfhi(t3.y)
            + bfhi(t4.y)+bfhi(t5.y)+bfhi(t6.y)+bfhi(t7.y);
        f4 += bflo(t0.z)+bflo(t1.z)+bflo(t2.z)+bflo(t3.z)
            + bflo(t4.z)+bflo(t5.z)+bflo(t6.z)+bflo(t7.z);
        f5 += bfhi(t0.z)+bfhi(t1.z)+bfhi(t2.z)+bfhi(t3.z)
            + bfhi(t4.z)+bfhi(t5.z)+bfhi(t6.z)+bfhi(t7.z);
        f6 += bflo(t0.w)+bflo(t1.w)+bflo(t2.w)+bflo(t3.w)
            + bflo(t4.w)+bflo(t5.w)+bflo(t6.w)+bflo(t7.w);
        f7 += bfhi(t0.w)+bfhi(t1.w)+bfhi(t2.w)+bfhi(t3.w)
            + bfhi(t4.w)+bfhi(t5.w)+bfhi(t6.w)+bfhi(t7.w);
    }
    for (; p + 4 <= cnt; p += 4) {
        int r0 = list[s + p + 0];
        int r1 = list[s + p + 1];
        int r2 = list[s + p + 2];
        int r3 = list[s + p + 3];
        uint4 t0 = *(const uint4*)(sp + (size_t)r0 * D);
        uint4 t1 = *(const uint4*)(sp + (size_t)r1 * D);
        uint4 t2 = *(const uint4*)(sp + (size_t)r2 * D);
        uint4 t3 = *(const uint4*)(sp + (size_t)r3 * D);
        f0 += bflo(t0.x) + bflo(t1.x) + bflo(t2.x) + bflo(t3.x);
        f1 += bfhi(t0.x) + bfhi(t1.x) + bfhi(t2.x) + bfhi(t3.x);
        f2 += bflo(t0.y) + bflo(t1.y) + bflo(t2.y) + bflo(t3.y);
        f3 += bfhi(t0.y) + bfhi(t1.y) + bfhi(t2.y) + bfhi(t3.y);
        f4 += bflo(t0.z) + bflo(t1.z) + bflo(t2.z) + bflo(t3.z);
        f5 += bfhi(t0.z) + bfhi(t1.z) + bfhi(t2.z) + bfhi(t3.z);
        f6 += bflo(t0.w) + bflo(t1.w) + bflo(t2.w) + bflo(t3.w);
        f7 += bfhi(t0.w) + bfhi(t1.w) + bfhi(t2.w) + bfhi(t3.w);
    }
    for (; p < cnt; ++p) {
        int r0 = list[s + p];
        uint4 t0 = *(const uint4*)(sp + (size_t)r0 * D);
        f0 += bflo(t0.x);  f1 += bfhi(t0.x);
        f2 += bflo(t0.y);  f3 += bfhi(t0.y);
        f4 += bflo(t0.z);  f5 += bfhi(t0.z);
        f6 += bflo(t0.w);  f7 += bfhi(t0.w);
    }

    float rc = recip[seg];
    f0 *= rc; f1 *= rc; f2 *= rc; f3 *= rc;
    f4 *= rc; f5 *= rc; f6 *= rc; f7 *= rc;
    if (uadd) {
        uint4 uv = *(const uint4*)(uadd + (size_t)seg * D + ql * 8);
        f0 = fmaxf(f0 + bflo(uv.x), 0.f);  f1 = fmaxf(f1 + bfhi(uv.x), 0.f);
        f2 = fmaxf(f2 + bflo(uv.y), 0.f);  f3 = fmaxf(f3 + bfhi(uv.y), 0.f);
        f4 = fmaxf(f4 + bflo(uv.z), 0.f);  f5 = fmaxf(f5 + bfhi(uv.z), 0.f);
        f6 = fmaxf(f6 + bflo(uv.w), 0.f);  f7 = fmaxf(f7 + bfhi(uv.w), 0.f);
    }
    if (headout) {
        float av[4];
        #pragma unroll
        for (int j = 0; j < 4; ++j) {
            const float* wr = Wa + j * D + ql * 8;
            float4 wA = *(const float4*)wr;
            float4 wB = *(const float4*)(wr + 4);
            float pj = f0 * wA.x + f1 * wA.y + f2 * wA.z + f3 * wA.w
                     + f4 * wB.x + f5 * wB.y + f6 * wB.z + f7 * wB.w;
            pj += __shfl_xor(pj, 1, 64);
            pj += __shfl_xor(pj, 2, 64);
            pj += __shfl_xor(pj, 4, 64);
            pj += __shfl_xor(pj, 8, 64);
            av[j] = pj + ba[j];
        }
        if (ql == 0) {
            float mx = fmaxf(fmaxf(av[0], av[1]), fmaxf(av[2], av[3]));
            float se = expf(av[0] - mx) + expf(av[1] - mx)
                     + expf(av[2] - mx) + expf(av[3] - mx);
            float lse = mx + logf(se);
            float4 o = make_float4(av[0] - lse, av[1] - lse, av[2] - lse, av[3] - lse);
            *(float4*)(headout + (size_t)seg * 4) = o;
        }
    } else {
        uint4 o;
        o.x = ((uint)f2bf(f1) << 16) | (uint)f2bf(f0);
        o.y = ((uint)f2bf(f3) << 16) | (uint)f2bf(f2);
        o.z = ((uint)f2bf(f5) << 16) | (uint)f2bf(f4);
        o.w = ((uint)f2bf(f7) << 16) | (uint)f2bf(f6);
        *(uint4*)(outbuf + (size_t)seg * D + ql * 8) = o;
    }
}

// ---------------------------------------------------------------- fused MLP + Wu (128-row blocks, 512 threads)
// Same LDS (70 KB -> 2 blocks/CU) but 8 waves/block -> 16 waves/CU (4/SIMD):
// each wave owns 16 rows; per-wave MFMA work halves, barrier latency hidden by
// 2x the resident waves. Epilogues store C-layout direct to global (R13/R14-
// validated). Block-barriered W-panel staging (proven R11 pattern).
__launch_bounds__(512, 4)
__global__ void mlp_fused(const void* __restrict__ Aptr, int a_fp32,
                          const ushort* __restrict__ W1b, // [256,128] bf16
                          const float* __restrict__ b1,
                          const ushort* __restrict__ W2b, // [128,256] bf16
                          const float* __restrict__ b2,
                          const ushort* __restrict__ Wub, // [128,128] bf16
                          const float* __restrict__ bu,
                          ushort* __restrict__ m2out,     // [M,128] bf16
                          ushort* __restrict__ uout,      // [M,128] bf16
                          int M) {
    __shared__ ushort Af[128][136];                // 34816 B
    __shared__ __align__(16) char Pbuf[18432];     // weight panel buffer
    __shared__ ushort m1c[128][72];                // 18432 B
    ushort* P = (ushort*)Pbuf;

    const int tid = threadIdx.x;                   // 0..511
    const int w = tid >> 6;                        // 0..7
    const int lane = tid & 63;
    const int quad = lane >> 4, mrow = lane & 15;
    const int rowBase = blockIdx.x * 128;
    const int wr0 = w * 16;                        // wave's 16-row slice

    // ---- stage A tile (128x128), fp32 or bf16 source ----
    #pragma unroll
    for (int r = 0; r < 4; ++r) {
        int idx = tid + r * 512;          // 0..2047
        int row = idx >> 4;               // 0..127
        int c   = (idx & 15) << 3;        // 0,8,...,120
        uint4 av = make_uint4(0, 0, 0, 0);
        if (rowBase + row < M) {
            if (a_fp32) {
                const float* ap = (const float*)Aptr + (size_t)(rowBase + row) * D + c;
                float4 va = *(const float4*)ap;
                float4 vb = *(const float4*)(ap + 4);
                av.x = ((uint)f2bf(va.y) << 16) | (uint)f2bf(va.x);
                av.y = ((uint)f2bf(va.w) << 16) | (uint)f2bf(va.z);
                av.z = ((uint)f2bf(vb.y) << 16) | (uint)f2bf(vb.x);
                av.w = ((uint)f2bf(vb.w) << 16) | (uint)f2bf(vb.z);
            } else {
                av = *(const uint4*)((const ushort*)Aptr + (size_t)(rowBase + row) * D + c);
            }
        }
        *(uint4*)&Af[row][c] = av;
    }

    // ---- phase C: u = Af @ Wu^T + bu (no relu), direct C-layout store ----
    for (int n0 = 0; n0 < D; n0 += 64) {
        __syncthreads();
        #pragma unroll
        for (int r = 0; r < 2; ++r) {
            int idx = tid + r * 512;      // 0..1023
            int row = idx >> 4;           // 0..63
            int c   = (idx & 15) << 3;
            *(uint4*)&P[row * 136 + c] = *(const uint4*)(Wub + (size_t)(n0 + row) * D + c);
        }
        __syncthreads();
        floatx4 acc[4] = {{0,0,0,0},{0,0,0,0},{0,0,0,0},{0,0,0,0}};
        #pragma unroll
        for (int k0 = 0; k0 < D; k0 += 32) {
            short8 af = *(const short8*)&Af[wr0 + mrow][k0 + quad * 8];
            #pragma unroll
            for (int t = 0; t < 4; ++t) {
                short8 bfr = *(const short8*)&P[(t * 16 + mrow) * 136 + k0 + quad * 8];
                acc[t] = __builtin_amdgcn_mfma_f32_16x16x32_bf16(af, bfr, acc[t], 0, 0, 0);
            }
        }
        int growb = rowBase + wr0 + quad * 4;
        if (growb < M) {
            #pragma unroll
            for (int t = 0; t < 4; ++t) {
                float bb = bu[n0 + t * 16 + mrow];
                #pragma unroll
                for (int r = 0; r < 4; ++r)
                    uout[(size_t)(growb + r) * D + n0 + t * 16 + mrow] =
                        f2bf(acc[t][r] + bb);
            }
        }
    }

    // ---- interleaved phase A/B over 64-col m1 chunks ----
    floatx4 acc2[8] = {};
    for (int kc = 0; kc < 4; ++kc) {
        __syncthreads();
        #pragma unroll
        for (int r = 0; r < 2; ++r) {
            int idx = tid + r * 512;
            int row = idx >> 4;
            int c   = (idx & 15) << 3;
            *(uint4*)&P[row * 136 + c] = *(const uint4*)(W1b + (size_t)(kc * 64 + row) * D + c);
        }
        __syncthreads();
        floatx4 acc1[4] = {{0,0,0,0},{0,0,0,0},{0,0,0,0},{0,0,0,0}};
        #pragma unroll
        for (int k0 = 0; k0 < D; k0 += 32) {
            short8 af = *(const short8*)&Af[wr0 + mrow][k0 + quad * 8];
            #pragma unroll
            for (int t = 0; t < 4; ++t) {
                short8 bfr = *(const short8*)&P[(t * 16 + mrow) * 136 + k0 + quad * 8];
                acc1[t] = __builtin_amdgcn_mfma_f32_16x16x32_bf16(af, bfr, acc1[t], 0, 0, 0);
            }
        }
        #pragma unroll
        for (int t = 0; t < 4; ++t) {
            float bb = b1[kc * 64 + t * 16 + mrow];
            #pragma unroll
            for (int r = 0; r < 4; ++r)
                m1c[wr0 + quad * 4 + r][t * 16 + mrow] =
                    f2bf(fmaxf(acc1[t][r] + bb, 0.f));
        }
        __syncthreads();   // all waves done reading W1 panel + m1c written
        #pragma unroll
        for (int r = 0; r < 2; ++r) {
            int idx = tid + r * 512;      // 0..1023
            int row = idx >> 3;           // 0..127
            int c8  = (idx & 7) << 3;     // 0..56
            *(uint4*)&P[row * 72 + c8] = *(const uint4*)(W2b + (size_t)row * H + kc * 64 + c8);
        }
        __syncthreads();
        #pragma unroll
        for (int k0 = 0; k0 < 64; k0 += 32) {
            short8 af = *(const short8*)&m1c[wr0 + mrow][k0 + quad * 8];
            #pragma unroll
            for (int t2 = 0; t2 < 8; ++t2) {
                short8 bfr = *(const short8*)&P[(t2 * 16 + mrow) * 72 + k0 + quad * 8];
                acc2[t2] = __builtin_amdgcn_mfma_f32_16x16x32_bf16(af, bfr, acc2[t2], 0, 0, 0);
            }
        }
    }

    // ---- m2 epilogue: direct C-layout stores ----
    {
        int growb = rowBase + wr0 + quad * 4;
        if (growb < M) {
            #pragma unroll
            for (int t2 = 0; t2 < 8; ++t2) {
                float bb = b2[t2 * 16 + mrow];
                #pragma unroll
                for (int r = 0; r < 4; ++r)
                    m2out[(size_t)(growb + r) * D + t2 * 16 + mrow] =
                        f2bf(fmaxf(acc2[t2][r] + bb, 0.f));
            }
        }
    }
}

// ---------------------------------------------------------------- launch
extern "C" void kernel_launch(void* const* d_in, const int* in_sizes, int n_in,
                              void* d_out, int out_size, void* d_ws, size_t ws_size,
                              hipStream_t stream) {
    const float* x     = (const float*)d_in[0];
    const int*   v_idx = (const int*)d_in[1];
    const int*   e_idx = (const int*)d_in[2];
    const float* W1    = (const float*)d_in[3];
    const float* b1    = (const float*)d_in[4];
    const float* W2    = (const float*)d_in[5];
    const float* b2    = (const float*)d_in[6];
    const float* Wu    = (const float*)d_in[7];
    const float* bu    = (const float*)d_in[8];
    const float* Wa    = (const float*)d_in[9];
    const float* ba    = (const float*)d_in[10];
    float* out = (float*)d_out;

    char* wsp = (char*)d_ws;
    auto alloc = [&](size_t bytes) -> char* {
        char* p = wsp;
        wsp += (bytes + 255) & ~(size_t)255;
        return p;
    };

    ushort* hA     = (ushort*)alloc((size_t)N_NODES * D * 2);
    ushort* m2b    = (ushort*)alloc((size_t)N_NODES * D * 2);
    ushort* ub     = (ushort*)alloc((size_t)N_NODES * D * 2);
    ushort* e_feat = (ushort*)alloc((size_t)N_EDGES * D * 2);
    ushort* W1b    = (ushort*)alloc((size_t)H * D * 2);
    ushort* W2b    = (ushort*)alloc((size_t)D * H * 2);
    ushort* Wub    = (ushort*)alloc((size_t)D * D * 2);
    int*    e_vert = (int*)alloc((size_t)NBE * CAPE * 4);
    int*    v_edge = (int*)alloc((size_t)NBV * CAPV * 4);
    int2*   recE   = (int2*)alloc((size_t)NBE * CAPE * 8);
    int2*   recV   = (int2*)alloc((size_t)NBV * CAPV * 8);
    int*    cntE   = (int*)alloc((size_t)(NBE + NBV) * 4);   // one memset covers both
    int*    cntV   = cntE + NBE;
    int2*   e_sd   = (int2*)alloc((size_t)N_EDGES * 8);
    int2*   v_sd   = (int2*)alloc((size_t)N_NODES * 8);
    float*  erecip = (float*)alloc((size_t)N_EDGES * 4);
    float*  vrecip = (float*)alloc((size_t)N_NODES * 4);

    const int cooBlocks  = (NNZ + CHUNK - 1) / CHUNK;   // 147
    const int convTotal  = H * D / 4 + D * H / 4 + D * D / 4;
    const int convBlocks = (convTotal + 255) / 256;     // 80

    hipMemsetAsync(cntE, 0, (size_t)(NBE + NBV) * 4, stream);
    convert_and_place<<<convBlocks + cooBlocks, 256, 0, stream>>>(
        W1, W1b, W2, W2b, Wu, Wub, v_idx, e_idx, cntE, cntV, recE, recV, convBlocks);
    bucket_final<<<NBE + NBV, 256, 0, stream>>>(recE, cntE, recV, cntV,
                                                e_sd, erecip, e_vert,
                                                v_sd, vrecip, v_edge);

    const int gridM = (N_NODES + 127) / 128;            // 391
    const int gEdge = (N_EDGES * 16 + 255) / 256;       // 1563
    const int gVert = (N_NODES * 16 + 255) / 256;       // 3125

    const void* h = x;
    int h_fp32 = 1;
    for (int depth = 0; depth < 2; ++depth) {
        mlp_fused<<<gridM, 512, 0, stream>>>(h, h_fp32, W1b, b1, W2b, b2, Wub, bu,
                                             m2b, ub, N_NODES);
        // e_feat[e] = erecip[e] * sum m2[v in e]
        gather_rows<<<gEdge, 256, 0, stream>>>(
            m2b, e_sd, e_vert, erecip, nullptr, e_feat, nullptr, nullptr, nullptr, N_EDGES);
        if (depth == 0) {
            // h1[v] = relu(u[v] + vrecip[v] * sum e_feat[e in v])
            gather_rows<<<gVert, 256, 0, stream>>>(
                e_feat, v_sd, v_edge, vrecip, ub, hA, nullptr, nullptr, nullptr, N_NODES);
            h = hA;
            h_fp32 = 0;
        } else {
            // final: fused head -> out = log_softmax(relu(u+agg) @ Wa^T + ba)
            gather_rows<<<gVert, 256, 0, stream>>>(
                e_feat, v_sd, v_edge, vrecip, ub, nullptr, Wa, ba, out, N_NODES);
        }
    }
}

// Round 17
// 259.787 us; speedup vs baseline: 1.0017x; 1.0017x over previous
//
#include <hip/hip_runtime.h>
#include <hip/hip_bf16.h>
#include <math.h>

#define N_NODES 50000
#define N_EDGES 25000
#define NNZ     600000
#define D       128
#define H       256

#define BW    98            // bucket width (segments per bucket)
#define NBE   256           // ceil(25000/98)
#define NBV   511           // ceil(50000/98)
#define CAPE  3072          // per-bucket record capacity, E (mean 2352, sd 48)
#define CAPV  1536          // per-bucket record capacity, V (mean 1176, sd 34)
#define CHUNK 4096          // COO items per block in place

typedef short short8 __attribute__((ext_vector_type(8)));
typedef float floatx4 __attribute__((ext_vector_type(4)));

__device__ inline ushort f2bf(float f) {              // RNE fp32 -> bf16
    uint u = __float_as_uint(f);
    u += 0x7FFF + ((u >> 16) & 1);
    return (ushort)(u >> 16);
}
__device__ inline float bflo(uint u) { return __uint_as_float(u << 16); }
__device__ inline float bfhi(uint u) { return __uint_as_float(u & 0xffff0000u); }

// ---------------------------------------------------------------- convert + CSR place (one dispatch)
__global__ void convert_and_place(const float* __restrict__ W1, ushort* __restrict__ W1b,
                                  const float* __restrict__ W2, ushort* __restrict__ W2b,
                                  const float* __restrict__ Wu, ushort* __restrict__ Wub,
                                  const int* __restrict__ v_idx, const int* __restrict__ e_idx,
                                  int* __restrict__ cntE, int* __restrict__ cntV,
                                  int2* __restrict__ recE, int2* __restrict__ recV,
                                  int convBlocks) {
    if ((int)blockIdx.x < convBlocks) {
        const int n1 = H * D / 4;
        const int n2 = D * H / 4;
        const int nu = D * D / 4;
        int j = blockIdx.x * 256 + threadIdx.x;
        const float* src; ushort* dst;
        if (j < n1)                { src = W1; dst = W1b; }
        else if ((j -= n1) < n2)   { src = W2; dst = W2b; }
        else if ((j -= n2) < nu)   { src = Wu; dst = Wub; }
        else return;
        float4 v = ((const float4*)src)[j];
        ushort4 o;
        o.x = f2bf(v.x); o.y = f2bf(v.y); o.z = f2bf(v.z); o.w = f2bf(v.w);
        ((ushort4*)dst)[j] = o;
        return;
    }

    __shared__ int hE[NBE], hV[NBV];
    __shared__ int rE[NBE], rV[NBV];
    for (int i = threadIdx.x; i < NBE; i += 256) hE[i] = 0;
    for (int i = threadIdx.x; i < NBV; i += 256) hV[i] = 0;
    __syncthreads();
    int base = (blockIdx.x - convBlocks) * CHUNK;
    int end  = min(base + CHUNK, NNZ);
    int myE[16], myV[16];
    #pragma unroll
    for (int j = 0; j < 16; ++j) {
        int i = base + threadIdx.x + j * 256;
        myE[j] = -1; myV[j] = -1;
        if (i < end) {
            myE[j] = e_idx[i];
            myV[j] = v_idx[i];
            atomicAdd(&hE[myE[j] / BW], 1);
            atomicAdd(&hV[myV[j] / BW], 1);
        }
    }
    __syncthreads();
    for (int i = threadIdx.x; i < NBE; i += 256) {
        int c = hE[i];
        rE[i] = c ? atomicAdd(&cntE[i], c) : 0;
    }
    for (int i = threadIdx.x; i < NBV; i += 256) {
        int c = hV[i];
        rV[i] = c ? atomicAdd(&cntV[i], c) : 0;
    }
    __syncthreads();
    for (int i = threadIdx.x; i < NBE; i += 256) hE[i] = 0;
    for (int i = threadIdx.x; i < NBV; i += 256) hV[i] = 0;
    __syncthreads();
    #pragma unroll
    for (int j = 0; j < 16; ++j) {
        if (myE[j] >= 0) {
            int bk = myE[j] / BW;
            int p = rE[bk] + atomicAdd(&hE[bk], 1);
            recE[(size_t)bk * CAPE + p] = make_int2(myE[j], myV[j]);
            bk = myV[j] / BW;
            p = rV[bk] + atomicAdd(&hV[bk], 1);
            recV[(size_t)bk * CAPV + p] = make_int2(myV[j], myE[j]);
        }
    }
}

// one block per bucket -> per-segment {start,count} descriptors + recip + adjacency
__global__ void bucket_final(const int2* __restrict__ recE, const int* __restrict__ cntE,
                             const int2* __restrict__ recV, const int* __restrict__ cntV,
                             int2* __restrict__ e_sd, float* __restrict__ erecip, int* __restrict__ e_vert,
                             int2* __restrict__ v_sd, float* __restrict__ vrecip, int* __restrict__ v_edge) {
    __shared__ int hist[BW], scn[BW], cur[BW];
    const bool eSide = blockIdx.x < NBE;
    const int b = eSide ? blockIdx.x : blockIdx.x - NBE;
    const int cap   = eSide ? CAPE : CAPV;
    const int2* rec = (eSide ? recE : recV) + (size_t)b * cap;
    const int cnt   = (eSide ? cntE : cntV)[b];
    const int nseg  = eSide ? N_EDGES : N_NODES;
    int2* sd        = eSide ? e_sd : v_sd;
    float* recip    = eSide ? erecip : vrecip;
    int* outv       = (eSide ? e_vert : v_edge) + (size_t)b * cap;
    const int k0 = b * BW;

    for (int i = threadIdx.x; i < BW; i += 256) hist[i] = 0;
    __syncthreads();
    for (int i = threadIdx.x; i < cnt; i += 256)
        atomicAdd(&hist[rec[i].x - k0], 1);
    __syncthreads();

    if (threadIdx.x < 64) {
        int lane = threadIdx.x;
        int v0 = hist[lane];
        int a = v0;
        #pragma unroll
        for (int d = 1; d < 64; d <<= 1) {
            int u = __shfl_up(a, d, 64);
            if (lane >= d) a += u;
        }
        scn[lane] = a - v0;
        int tot0 = __shfl(a, 63, 64);
        int v1 = (lane < BW - 64) ? hist[64 + lane] : 0;
        int a1 = v1;
        #pragma unroll
        for (int d = 1; d < 64; d <<= 1) {
            int u = __shfl_up(a1, d, 64);
            if (lane >= d) a1 += u;
        }
        if (lane < BW - 64) scn[64 + lane] = tot0 + a1 - v1;
    }
    __syncthreads();

    const int gbase = b * cap;
    for (int i = threadIdx.x; i < BW; i += 256) {
        int seg = k0 + i;
        if (seg < nseg) {
            sd[seg] = make_int2(gbase + scn[i], hist[i]);
            recip[seg] = 1.0f / (float)max(hist[i], 1);
        }
        cur[i] = scn[i];
    }
    __syncthreads();
    for (int i = threadIdx.x; i < cnt; i += 256) {
        int2 r = rec[i];
        int p = atomicAdd(&cur[r.x - k0], 1);
        outv[p] = r.y;
    }
}

// ---------------------------------------------------------------- gather (one segment per 16-lane quarter)
// R11/R14-proven inner loop: 4 direct index loads per round, 4 row loads in flight.
__global__ void gather_rows(const ushort* __restrict__ src,
                            const int2* __restrict__ sd,
                            const int* __restrict__ list,
                            const float* __restrict__ recip,
                            const ushort* __restrict__ uadd,
                            ushort* __restrict__ outbuf,
                            const float* __restrict__ Wa,
                            const float* __restrict__ ba,
                            float* __restrict__ headout,
                            int nseg) {
    long long gtid = (long long)blockIdx.x * blockDim.x + threadIdx.x;
    int seg = (int)(gtid >> 4);           // one segment per 16 lanes
    int ql  = threadIdx.x & 15;           // feature group: 8 features at ql*8
    if (seg >= nseg) return;
    int2 dsc = sd[seg];
    int s = dsc.x, cnt = dsc.y;
    const ushort* sp = src + ql * 8;

    float f0 = 0.f, f1 = 0.f, f2 = 0.f, f3 = 0.f;
    float f4 = 0.f, f5 = 0.f, f6 = 0.f, f7 = 0.f;

    int p = 0;
    for (; p + 4 <= cnt; p += 4) {
        int r0 = list[s + p + 0];
        int r1 = list[s + p + 1];
        int r2 = list[s + p + 2];
        int r3 = list[s + p + 3];
        uint4 t0 = *(const uint4*)(sp + (size_t)r0 * D);
        uint4 t1 = *(const uint4*)(sp + (size_t)r1 * D);
        uint4 t2 = *(const uint4*)(sp + (size_t)r2 * D);
        uint4 t3 = *(const uint4*)(sp + (size_t)r3 * D);
        f0 += bflo(t0.x) + bflo(t1.x) + bflo(t2.x) + bflo(t3.x);
        f1 += bfhi(t0.x) + bfhi(t1.x) + bfhi(t2.x) + bfhi(t3.x);
        f2 += bflo(t0.y) + bflo(t1.y) + bflo(t2.y) + bflo(t3.y);
        f3 += bfhi(t0.y) + bfhi(t1.y) + bfhi(t2.y) + bfhi(t3.y);
        f4 += bflo(t0.z) + bflo(t1.z) + bflo(t2.z) + bflo(t3.z);
        f5 += bfhi(t0.z) + bfhi(t1.z) + bfhi(t2.z) + bfhi(t3.z);
        f6 += bflo(t0.w) + bflo(t1.w) + bflo(t2.w) + bflo(t3.w);
        f7 += bfhi(t0.w) + bfhi(t1.w) + bfhi(t2.w) + bfhi(t3.w);
    }
    for (; p < cnt; ++p) {
        int r0 = list[s + p];
        uint4 t0 = *(const uint4*)(sp + (size_t)r0 * D);
        f0 += bflo(t0.x);  f1 += bfhi(t0.x);
        f2 += bflo(t0.y);  f3 += bfhi(t0.y);
        f4 += bflo(t0.z);  f5 += bfhi(t0.z);
        f6 += bflo(t0.w);  f7 += bfhi(t0.w);
    }

    float rc = recip[seg];
    f0 *= rc; f1 *= rc; f2 *= rc; f3 *= rc;
    f4 *= rc; f5 *= rc; f6 *= rc; f7 *= rc;
    if (uadd) {
        uint4 uv = *(const uint4*)(uadd + (size_t)seg * D + ql * 8);
        f0 = fmaxf(f0 + bflo(uv.x), 0.f);  f1 = fmaxf(f1 + bfhi(uv.x), 0.f);
        f2 = fmaxf(f2 + bflo(uv.y), 0.f);  f3 = fmaxf(f3 + bfhi(uv.y), 0.f);
        f4 = fmaxf(f4 + bflo(uv.z), 0.f);  f5 = fmaxf(f5 + bfhi(uv.z), 0.f);
        f6 = fmaxf(f6 + bflo(uv.w), 0.f);  f7 = fmaxf(f7 + bfhi(uv.w), 0.f);
    }
    if (headout) {
        float av[4];
        #pragma unroll
        for (int j = 0; j < 4; ++j) {
            const float* wr = Wa + j * D + ql * 8;
            float4 wA = *(const float4*)wr;
            float4 wB = *(const float4*)(wr + 4);
            float pj = f0 * wA.x + f1 * wA.y + f2 * wA.z + f3 * wA.w
                     + f4 * wB.x + f5 * wB.y + f6 * wB.z + f7 * wB.w;
            pj += __shfl_xor(pj, 1, 64);
            pj += __shfl_xor(pj, 2, 64);
            pj += __shfl_xor(pj, 4, 64);
            pj += __shfl_xor(pj, 8, 64);
            av[j] = pj + ba[j];
        }
        if (ql == 0) {
            float mx = fmaxf(fmaxf(av[0], av[1]), fmaxf(av[2], av[3]));
            float se = expf(av[0] - mx) + expf(av[1] - mx)
                     + expf(av[2] - mx) + expf(av[3] - mx);
            float lse = mx + logf(se);
            float4 o = make_float4(av[0] - lse, av[1] - lse, av[2] - lse, av[3] - lse);
            *(float4*)(headout + (size_t)seg * 4) = o;
        }
    } else {
        uint4 o;
        o.x = ((uint)f2bf(f1) << 16) | (uint)f2bf(f0);
        o.y = ((uint)f2bf(f3) << 16) | (uint)f2bf(f2);
        o.z = ((uint)f2bf(f5) << 16) | (uint)f2bf(f4);
        o.w = ((uint)f2bf(f7) << 16) | (uint)f2bf(f6);
        *(uint4*)(outbuf + (size_t)seg * D + ql * 8) = o;
    }
}

// ---------------------------------------------------------------- fused MLP + Wu (64-row blocks, 3 blocks/CU)
// 45 KB LDS (Af 17.4 + P 18.4 + m1c 9.2) -> 3 blocks/CU (12 waves) vs R14's 2.
// 4 waves/block (proven barrier skew); direct C-layout epilogues (proven).
// Each wave owns 16 rows; m1c handoff is same-wave rows (no extra barrier).
__launch_bounds__(256, 3)
__global__ void mlp_fused(const void* __restrict__ Aptr, int a_fp32,
                          const ushort* __restrict__ W1b, // [256,128] bf16
                          const float* __restrict__ b1,
                          const ushort* __restrict__ W2b, // [128,256] bf16
                          const float* __restrict__ b2,
                          const ushort* __restrict__ Wub, // [128,128] bf16
                          const float* __restrict__ bu,
                          ushort* __restrict__ m2out,     // [M,128] bf16
                          ushort* __restrict__ uout,      // [M,128] bf16
                          int M) {
    __shared__ ushort Af[64][136];                 // 17408 B
    __shared__ __align__(16) char Pbuf[18432];     // weight panel buffer
    __shared__ ushort m1c[64][72];                 // 9216 B
    ushort* P = (ushort*)Pbuf;

    const int tid = threadIdx.x;
    const int w = tid >> 6, lane = tid & 63;
    const int quad = lane >> 4, mrow = lane & 15;
    const int rowBase = blockIdx.x * 64;
    const int wr0 = w * 16;                        // wave's 16-row slice

    // ---- stage A tile (64x128), fp32 or bf16 source ----
    #pragma unroll
    for (int r = 0; r < 4; ++r) {
        int idx = tid + r * 256;          // 0..1023
        int row = idx >> 4;               // 0..63
        int c   = (idx & 15) << 3;        // 0,8,...,120
        uint4 av = make_uint4(0, 0, 0, 0);
        if (rowBase + row < M) {
            if (a_fp32) {
                const float* ap = (const float*)Aptr + (size_t)(rowBase + row) * D + c;
                float4 va = *(const float4*)ap;
                float4 vb = *(const float4*)(ap + 4);
                av.x = ((uint)f2bf(va.y) << 16) | (uint)f2bf(va.x);
                av.y = ((uint)f2bf(va.w) << 16) | (uint)f2bf(va.z);
                av.z = ((uint)f2bf(vb.y) << 16) | (uint)f2bf(vb.x);
                av.w = ((uint)f2bf(vb.w) << 16) | (uint)f2bf(vb.z);
            } else {
                av = *(const uint4*)((const ushort*)Aptr + (size_t)(rowBase + row) * D + c);
            }
        }
        *(uint4*)&Af[row][c] = av;
    }

    // ---- phase C: u = Af @ Wu^T + bu (no relu), direct C-layout store ----
    for (int n0 = 0; n0 < D; n0 += 64) {
        __syncthreads();
        #pragma unroll
        for (int r = 0; r < 4; ++r) {
            int idx = tid + r * 256;
            int row = idx >> 4;
            int c   = (idx & 15) << 3;
            *(uint4*)&P[row * 136 + c] = *(const uint4*)(Wub + (size_t)(n0 + row) * D + c);
        }
        __syncthreads();
        floatx4 acc[4] = {{0,0,0,0},{0,0,0,0},{0,0,0,0},{0,0,0,0}};
        #pragma unroll
        for (int k0 = 0; k0 < D; k0 += 32) {
            short8 af = *(const short8*)&Af[wr0 + mrow][k0 + quad * 8];
            #pragma unroll
            for (int t = 0; t < 4; ++t) {
                short8 bfr = *(const short8*)&P[(t * 16 + mrow) * 136 + k0 + quad * 8];
                acc[t] = __builtin_amdgcn_mfma_f32_16x16x32_bf16(af, bfr, acc[t], 0, 0, 0);
            }
        }
        int growb = rowBase + wr0 + quad * 4;
        if (growb < M) {
            #pragma unroll
            for (int t = 0; t < 4; ++t) {
                float bb = bu[n0 + t * 16 + mrow];
                #pragma unroll
                for (int r = 0; r < 4; ++r)
                    uout[(size_t)(growb + r) * D + n0 + t * 16 + mrow] =
                        f2bf(acc[t][r] + bb);
            }
        }
    }

    // ---- interleaved phase A/B over 64-col m1 chunks ----
    floatx4 acc2[8] = {};
    for (int kc = 0; kc < 4; ++kc) {
        __syncthreads();
        #pragma unroll
        for (int r = 0; r < 4; ++r) {
            int idx = tid + r * 256;
            int row = idx >> 4;
            int c   = (idx & 15) << 3;
            *(uint4*)&P[row * 136 + c] = *(const uint4*)(W1b + (size_t)(kc * 64 + row) * D + c);
        }
        __syncthreads();
        floatx4 acc1[4] = {{0,0,0,0},{0,0,0,0},{0,0,0,0},{0,0,0,0}};
        #pragma unroll
        for (int k0 = 0; k0 < D; k0 += 32) {
            short8 af = *(const short8*)&Af[wr0 + mrow][k0 + quad * 8];
            #pragma unroll
            for (int t = 0; t < 4; ++t) {
                short8 bfr = *(const short8*)&P[(t * 16 + mrow) * 136 + k0 + quad * 8];
                acc1[t] = __builtin_amdgcn_mfma_f32_16x16x32_bf16(af, bfr, acc1[t], 0, 0, 0);
            }
        }
        #pragma unroll
        for (int t = 0; t < 4; ++t) {
            float bb = b1[kc * 64 + t * 16 + mrow];
            #pragma unroll
            for (int r = 0; r < 4; ++r)
                m1c[wr0 + quad * 4 + r][t * 16 + mrow] =
                    f2bf(fmaxf(acc1[t][r] + bb, 0.f));
        }
        __syncthreads();   // all waves done reading W1 panel
        #pragma unroll
        for (int r = 0; r < 4; ++r) {
            int idx = tid + r * 256;      // 0..1023
            int row = idx >> 3;           // 0..127
            int c8  = (idx & 7) << 3;     // 0..56
            *(uint4*)&P[row * 72 + c8] = *(const uint4*)(W2b + (size_t)row * H + kc * 64 + c8);
        }
        __syncthreads();
        #pragma unroll
        for (int k0 = 0; k0 < 64; k0 += 32) {
            short8 af = *(const short8*)&m1c[wr0 + mrow][k0 + quad * 8];
            #pragma unroll
            for (int t2 = 0; t2 < 8; ++t2) {
                short8 bfr = *(const short8*)&P[(t2 * 16 + mrow) * 72 + k0 + quad * 8];
                acc2[t2] = __builtin_amdgcn_mfma_f32_16x16x32_bf16(af, bfr, acc2[t2], 0, 0, 0);
            }
        }
    }

    // ---- m2 epilogue: direct C-layout stores ----
    {
        int growb = rowBase + wr0 + quad * 4;
        if (growb < M) {
            #pragma unroll
            for (int t2 = 0; t2 < 8; ++t2) {
                float bb = b2[t2 * 16 + mrow];
                #pragma unroll
                for (int r = 0; r < 4; ++r)
                    m2out[(size_t)(growb + r) * D + t2 * 16 + mrow] =
                        f2bf(fmaxf(acc2[t2][r] + bb, 0.f));
            }
        }
    }
}

// ---------------------------------------------------------------- launch
extern "C" void kernel_launch(void* const* d_in, const int* in_sizes, int n_in,
                              void* d_out, int out_size, void* d_ws, size_t ws_size,
                              hipStream_t stream) {
    const float* x     = (const float*)d_in[0];
    const int*   v_idx = (const int*)d_in[1];
    const int*   e_idx = (const int*)d_in[2];
    const float* W1    = (const float*)d_in[3];
    const float* b1    = (const float*)d_in[4];
    const float* W2    = (const float*)d_in[5];
    const float* b2    = (const float*)d_in[6];
    const float* Wu    = (const float*)d_in[7];
    const float* bu    = (const float*)d_in[8];
    const float* Wa    = (const float*)d_in[9];
    const float* ba    = (const float*)d_in[10];
    float* out = (float*)d_out;

    char* wsp = (char*)d_ws;
    auto alloc = [&](size_t bytes) -> char* {
        char* p = wsp;
        wsp += (bytes + 255) & ~(size_t)255;
        return p;
    };

    ushort* hA     = (ushort*)alloc((size_t)N_NODES * D * 2);
    ushort* m2b    = (ushort*)alloc((size_t)N_NODES * D * 2);
    ushort* ub     = (ushort*)alloc((size_t)N_NODES * D * 2);
    ushort* e_feat = (ushort*)alloc((size_t)N_EDGES * D * 2);
    ushort* W1b    = (ushort*)alloc((size_t)H * D * 2);
    ushort* W2b    = (ushort*)alloc((size_t)D * H * 2);
    ushort* Wub    = (ushort*)alloc((size_t)D * D * 2);
    int*    e_vert = (int*)alloc((size_t)NBE * CAPE * 4);
    int*    v_edge = (int*)alloc((size_t)NBV * CAPV * 4);
    int2*   recE   = (int2*)alloc((size_t)NBE * CAPE * 8);
    int2*   recV   = (int2*)alloc((size_t)NBV * CAPV * 8);
    int*    cntE   = (int*)alloc((size_t)(NBE + NBV) * 4);   // one memset covers both
    int*    cntV   = cntE + NBE;
    int2*   e_sd   = (int2*)alloc((size_t)N_EDGES * 8);
    int2*   v_sd   = (int2*)alloc((size_t)N_NODES * 8);
    float*  erecip = (float*)alloc((size_t)N_EDGES * 4);
    float*  vrecip = (float*)alloc((size_t)N_NODES * 4);

    const int cooBlocks  = (NNZ + CHUNK - 1) / CHUNK;   // 147
    const int convTotal  = H * D / 4 + D * H / 4 + D * D / 4;
    const int convBlocks = (convTotal + 255) / 256;     // 80

    hipMemsetAsync(cntE, 0, (size_t)(NBE + NBV) * 4, stream);
    convert_and_place<<<convBlocks + cooBlocks, 256, 0, stream>>>(
        W1, W1b, W2, W2b, Wu, Wub, v_idx, e_idx, cntE, cntV, recE, recV, convBlocks);
    bucket_final<<<NBE + NBV, 256, 0, stream>>>(recE, cntE, recV, cntV,
                                                e_sd, erecip, e_vert,
                                                v_sd, vrecip, v_edge);

    const int gridM = (N_NODES + 63) / 64;              // 782
    const int gEdge = (N_EDGES * 16 + 255) / 256;       // 1563
    const int gVert = (N_NODES * 16 + 255) / 256;       // 3125

    const void* h = x;
    int h_fp32 = 1;
    for (int depth = 0; depth < 2; ++depth) {
        mlp_fused<<<gridM, 256, 0, stream>>>(h, h_fp32, W1b, b1, W2b, b2, Wub, bu,
                                             m2b, ub, N_NODES);
        // e_feat[e] = erecip[e] * sum m2[v in e]
        gather_rows<<<gEdge, 256, 0, stream>>>(
            m2b, e_sd, e_vert, erecip, nullptr, e_feat, nullptr, nullptr, nullptr, N_EDGES);
        if (depth == 0) {
            // h1[v] = relu(u[v] + vrecip[v] * sum e_feat[e in v])
            gather_rows<<<gVert, 256, 0, stream>>>(
                e_feat, v_sd, v_edge, vrecip, ub, hA, nullptr, nullptr, nullptr, N_NODES);
            h = hA;
            h_fp32 = 0;
        } else {
            // final: fused head -> out = log_softmax(relu(u+agg) @ Wa^T + ba)
            gather_rows<<<gVert, 256, 0, stream>>>(
                e_feat, v_sd, v_edge, vrecip, ub, nullptr, Wa, ba, out, N_NODES);
        }
    }
}

// Round 18
// 252.352 us; speedup vs baseline: 1.0312x; 1.0295x over previous
//
#include <hip/hip_runtime.h>
#include <hip/hip_bf16.h>
#include <math.h>

#define N_NODES 50000
#define N_EDGES 25000
#define NNZ     600000
#define D       128
#define H       256

#define BW    98            // bucket width (segments per bucket)
#define NBE   256           // ceil(25000/98)
#define NBV   511           // ceil(50000/98)
#define CAPE  3072          // per-bucket record capacity, E (mean 2352, sd 48)
#define CAPV  1536          // per-bucket record capacity, V (mean 1176, sd 34)
#define CHUNK 4096          // COO items per block in place

typedef short short8 __attribute__((ext_vector_type(8)));
typedef float floatx4 __attribute__((ext_vector_type(4)));

__device__ inline ushort f2bf(float f) {              // RNE fp32 -> bf16
    uint u = __float_as_uint(f);
    u += 0x7FFF + ((u >> 16) & 1);
    return (ushort)(u >> 16);
}
__device__ inline float bflo(uint u) { return __uint_as_float(u << 16); }
__device__ inline float bfhi(uint u) { return __uint_as_float(u & 0xffff0000u); }

// ---------------------------------------------------------------- convert + CSR place (one dispatch)
__global__ void convert_and_place(const float* __restrict__ W1, ushort* __restrict__ W1b,
                                  const float* __restrict__ W2, ushort* __restrict__ W2b,
                                  const float* __restrict__ Wu, ushort* __restrict__ Wub,
                                  const int* __restrict__ v_idx, const int* __restrict__ e_idx,
                                  int* __restrict__ cntE, int* __restrict__ cntV,
                                  int2* __restrict__ recE, int2* __restrict__ recV,
                                  int convBlocks) {
    if ((int)blockIdx.x < convBlocks) {
        const int n1 = H * D / 4;
        const int n2 = D * H / 4;
        const int nu = D * D / 4;
        int j = blockIdx.x * 256 + threadIdx.x;
        const float* src; ushort* dst;
        if (j < n1)                { src = W1; dst = W1b; }
        else if ((j -= n1) < n2)   { src = W2; dst = W2b; }
        else if ((j -= n2) < nu)   { src = Wu; dst = Wub; }
        else return;
        float4 v = ((const float4*)src)[j];
        ushort4 o;
        o.x = f2bf(v.x); o.y = f2bf(v.y); o.z = f2bf(v.z); o.w = f2bf(v.w);
        ((ushort4*)dst)[j] = o;
        return;
    }

    __shared__ int hE[NBE], hV[NBV];
    __shared__ int rE[NBE], rV[NBV];
    for (int i = threadIdx.x; i < NBE; i += 256) hE[i] = 0;
    for (int i = threadIdx.x; i < NBV; i += 256) hV[i] = 0;
    __syncthreads();
    int base = (blockIdx.x - convBlocks) * CHUNK;
    int end  = min(base + CHUNK, NNZ);
    int myE[16], myV[16];
    #pragma unroll
    for (int j = 0; j < 16; ++j) {
        int i = base + threadIdx.x + j * 256;
        myE[j] = -1; myV[j] = -1;
        if (i < end) {
            myE[j] = e_idx[i];
            myV[j] = v_idx[i];
            atomicAdd(&hE[myE[j] / BW], 1);
            atomicAdd(&hV[myV[j] / BW], 1);
        }
    }
    __syncthreads();
    for (int i = threadIdx.x; i < NBE; i += 256) {
        int c = hE[i];
        rE[i] = c ? atomicAdd(&cntE[i], c) : 0;
    }
    for (int i = threadIdx.x; i < NBV; i += 256) {
        int c = hV[i];
        rV[i] = c ? atomicAdd(&cntV[i], c) : 0;
    }
    __syncthreads();
    for (int i = threadIdx.x; i < NBE; i += 256) hE[i] = 0;
    for (int i = threadIdx.x; i < NBV; i += 256) hV[i] = 0;
    __syncthreads();
    #pragma unroll
    for (int j = 0; j < 16; ++j) {
        if (myE[j] >= 0) {
            int bk = myE[j] / BW;
            int p = rE[bk] + atomicAdd(&hE[bk], 1);
            recE[(size_t)bk * CAPE + p] = make_int2(myE[j], myV[j]);
            bk = myV[j] / BW;
            p = rV[bk] + atomicAdd(&hV[bk], 1);
            recV[(size_t)bk * CAPV + p] = make_int2(myV[j], myE[j]);
        }
    }
}

// one block per bucket -> per-segment {start,count} descriptors + recip + adjacency
__global__ void bucket_final(const int2* __restrict__ recE, const int* __restrict__ cntE,
                             const int2* __restrict__ recV, const int* __restrict__ cntV,
                             int2* __restrict__ e_sd, float* __restrict__ erecip, int* __restrict__ e_vert,
                             int2* __restrict__ v_sd, float* __restrict__ vrecip, int* __restrict__ v_edge) {
    __shared__ int hist[BW], scn[BW], cur[BW];
    const bool eSide = blockIdx.x < NBE;
    const int b = eSide ? blockIdx.x : blockIdx.x - NBE;
    const int cap   = eSide ? CAPE : CAPV;
    const int2* rec = (eSide ? recE : recV) + (size_t)b * cap;
    const int cnt   = (eSide ? cntE : cntV)[b];
    const int nseg  = eSide ? N_EDGES : N_NODES;
    int2* sd        = eSide ? e_sd : v_sd;
    float* recip    = eSide ? erecip : vrecip;
    int* outv       = (eSide ? e_vert : v_edge) + (size_t)b * cap;
    const int k0 = b * BW;

    for (int i = threadIdx.x; i < BW; i += 256) hist[i] = 0;
    __syncthreads();
    for (int i = threadIdx.x; i < cnt; i += 256)
        atomicAdd(&hist[rec[i].x - k0], 1);
    __syncthreads();

    if (threadIdx.x < 64) {
        int lane = threadIdx.x;
        int v0 = hist[lane];
        int a = v0;
        #pragma unroll
        for (int d = 1; d < 64; d <<= 1) {
            int u = __shfl_up(a, d, 64);
            if (lane >= d) a += u;
        }
        scn[lane] = a - v0;
        int tot0 = __shfl(a, 63, 64);
        int v1 = (lane < BW - 64) ? hist[64 + lane] : 0;
        int a1 = v1;
        #pragma unroll
        for (int d = 1; d < 64; d <<= 1) {
            int u = __shfl_up(a1, d, 64);
            if (lane >= d) a1 += u;
        }
        if (lane < BW - 64) scn[64 + lane] = tot0 + a1 - v1;
    }
    __syncthreads();

    const int gbase = b * cap;
    for (int i = threadIdx.x; i < BW; i += 256) {
        int seg = k0 + i;
        if (seg < nseg) {
            sd[seg] = make_int2(gbase + scn[i], hist[i]);
            recip[seg] = 1.0f / (float)max(hist[i], 1);
        }
        cur[i] = scn[i];
    }
    __syncthreads();
    for (int i = threadIdx.x; i < cnt; i += 256) {
        int2 r = rec[i];
        int p = atomicAdd(&cur[r.x - k0], 1);
        outv[p] = r.y;
    }
}

// ---------------------------------------------------------------- gather (one segment per 16-lane quarter)
// R11/R14-proven inner loop: 4 direct index loads per round, 4 row loads in flight.
__global__ void gather_rows(const ushort* __restrict__ src,
                            const int2* __restrict__ sd,
                            const int* __restrict__ list,
                            const float* __restrict__ recip,
                            const ushort* __restrict__ uadd,
                            ushort* __restrict__ outbuf,
                            const float* __restrict__ Wa,
                            const float* __restrict__ ba,
                            float* __restrict__ headout,
                            int nseg) {
    long long gtid = (long long)blockIdx.x * blockDim.x + threadIdx.x;
    int seg = (int)(gtid >> 4);           // one segment per 16 lanes
    int ql  = threadIdx.x & 15;           // feature group: 8 features at ql*8
    if (seg >= nseg) return;
    int2 dsc = sd[seg];
    int s = dsc.x, cnt = dsc.y;
    const ushort* sp = src + ql * 8;

    float f0 = 0.f, f1 = 0.f, f2 = 0.f, f3 = 0.f;
    float f4 = 0.f, f5 = 0.f, f6 = 0.f, f7 = 0.f;

    int p = 0;
    for (; p + 4 <= cnt; p += 4) {
        int r0 = list[s + p + 0];
        int r1 = list[s + p + 1];
        int r2 = list[s + p + 2];
        int r3 = list[s + p + 3];
        uint4 t0 = *(const uint4*)(sp + (size_t)r0 * D);
        uint4 t1 = *(const uint4*)(sp + (size_t)r1 * D);
        uint4 t2 = *(const uint4*)(sp + (size_t)r2 * D);
        uint4 t3 = *(const uint4*)(sp + (size_t)r3 * D);
        f0 += bflo(t0.x) + bflo(t1.x) + bflo(t2.x) + bflo(t3.x);
        f1 += bfhi(t0.x) + bfhi(t1.x) + bfhi(t2.x) + bfhi(t3.x);
        f2 += bflo(t0.y) + bflo(t1.y) + bflo(t2.y) + bflo(t3.y);
        f3 += bfhi(t0.y) + bfhi(t1.y) + bfhi(t2.y) + bfhi(t3.y);
        f4 += bflo(t0.z) + bflo(t1.z) + bflo(t2.z) + bflo(t3.z);
        f5 += bfhi(t0.z) + bfhi(t1.z) + bfhi(t2.z) + bfhi(t3.z);
        f6 += bflo(t0.w) + bflo(t1.w) + bflo(t2.w) + bflo(t3.w);
        f7 += bfhi(t0.w) + bfhi(t1.w) + bfhi(t2.w) + bfhi(t3.w);
    }
    for (; p < cnt; ++p) {
        int r0 = list[s + p];
        uint4 t0 = *(const uint4*)(sp + (size_t)r0 * D);
        f0 += bflo(t0.x);  f1 += bfhi(t0.x);
        f2 += bflo(t0.y);  f3 += bfhi(t0.y);
        f4 += bflo(t0.z);  f5 += bfhi(t0.z);
        f6 += bflo(t0.w);  f7 += bfhi(t0.w);
    }

    float rc = recip[seg];
    f0 *= rc; f1 *= rc; f2 *= rc; f3 *= rc;
    f4 *= rc; f5 *= rc; f6 *= rc; f7 *= rc;
    if (uadd) {
        uint4 uv = *(const uint4*)(uadd + (size_t)seg * D + ql * 8);
        f0 = fmaxf(f0 + bflo(uv.x), 0.f);  f1 = fmaxf(f1 + bfhi(uv.x), 0.f);
        f2 = fmaxf(f2 + bflo(uv.y), 0.f);  f3 = fmaxf(f3 + bfhi(uv.y), 0.f);
        f4 = fmaxf(f4 + bflo(uv.z), 0.f);  f5 = fmaxf(f5 + bfhi(uv.z), 0.f);
        f6 = fmaxf(f6 + bflo(uv.w), 0.f);  f7 = fmaxf(f7 + bfhi(uv.w), 0.f);
    }
    if (headout) {
        float av[4];
        #pragma unroll
        for (int j = 0; j < 4; ++j) {
            const float* wr = Wa + j * D + ql * 8;
            float4 wA = *(const float4*)wr;
            float4 wB = *(const float4*)(wr + 4);
            float pj = f0 * wA.x + f1 * wA.y + f2 * wA.z + f3 * wA.w
                     + f4 * wB.x + f5 * wB.y + f6 * wB.z + f7 * wB.w;
            pj += __shfl_xor(pj, 1, 64);
            pj += __shfl_xor(pj, 2, 64);
            pj += __shfl_xor(pj, 4, 64);
            pj += __shfl_xor(pj, 8, 64);
            av[j] = pj + ba[j];
        }
        if (ql == 0) {
            float mx = fmaxf(fmaxf(av[0], av[1]), fmaxf(av[2], av[3]));
            float se = expf(av[0] - mx) + expf(av[1] - mx)
                     + expf(av[2] - mx) + expf(av[3] - mx);
            float lse = mx + logf(se);
            float4 o = make_float4(av[0] - lse, av[1] - lse, av[2] - lse, av[3] - lse);
            *(float4*)(headout + (size_t)seg * 4) = o;
        }
    } else {
        uint4 o;
        o.x = ((uint)f2bf(f1) << 16) | (uint)f2bf(f0);
        o.y = ((uint)f2bf(f3) << 16) | (uint)f2bf(f2);
        o.z = ((uint)f2bf(f5) << 16) | (uint)f2bf(f4);
        o.w = ((uint)f2bf(f7) << 16) | (uint)f2bf(f6);
        *(uint4*)(outbuf + (size_t)seg * D + ql * 8) = o;
    }
}

// ---------------------------------------------------------------- fused MLP + Wu (128-row blocks)
// R14 best-known configuration: LDS weight panels (proven), 256 threads,
// 2 blocks/CU, direct C-layout epilogue stores (no transpose slab).
__launch_bounds__(256, 2)
__global__ void mlp_fused(const void* __restrict__ Aptr, int a_fp32,
                          const ushort* __restrict__ W1b, // [256,128] bf16
                          const float* __restrict__ b1,
                          const ushort* __restrict__ W2b, // [128,256] bf16
                          const float* __restrict__ b2,
                          const ushort* __restrict__ Wub, // [128,128] bf16
                          const float* __restrict__ bu,
                          ushort* __restrict__ m2out,     // [M,128] bf16
                          ushort* __restrict__ uout,      // [M,128] bf16
                          int M) {
    __shared__ ushort Af[128][136];                // 34816 B
    __shared__ __align__(16) char Pbuf[18432];     // weight panel buffer
    __shared__ ushort m1c[128][72];                // 18432 B
    ushort* P = (ushort*)Pbuf;

    const int tid = threadIdx.x;
    const int w = tid >> 6, lane = tid & 63;
    const int quad = lane >> 4, mrow = lane & 15;
    const int rowBase = blockIdx.x * 128;

    // ---- stage A tile (128x128), fp32 or bf16 source ----
    #pragma unroll
    for (int r = 0; r < 8; ++r) {
        int idx = tid + r * 256;          // 0..2047
        int row = idx >> 4;               // 0..127
        int c   = (idx & 15) << 3;        // 0,8,...,120
        uint4 av = make_uint4(0, 0, 0, 0);
        if (rowBase + row < M) {
            if (a_fp32) {
                const float* ap = (const float*)Aptr + (size_t)(rowBase + row) * D + c;
                float4 va = *(const float4*)ap;
                float4 vb = *(const float4*)(ap + 4);
                av.x = ((uint)f2bf(va.y) << 16) | (uint)f2bf(va.x);
                av.y = ((uint)f2bf(va.w) << 16) | (uint)f2bf(va.z);
                av.z = ((uint)f2bf(vb.y) << 16) | (uint)f2bf(vb.x);
                av.w = ((uint)f2bf(vb.w) << 16) | (uint)f2bf(vb.z);
            } else {
                av = *(const uint4*)((const ushort*)Aptr + (size_t)(rowBase + row) * D + c);
            }
        }
        *(uint4*)&Af[row][c] = av;
    }

    // ---- phase C: u = Af @ Wu^T + bu (no relu), direct C-layout store ----
    for (int n0 = 0; n0 < D; n0 += 64) {
        __syncthreads();
        #pragma unroll
        for (int r = 0; r < 4; ++r) {
            int idx = tid + r * 256;
            int row = idx >> 4;
            int c   = (idx & 15) << 3;
            *(uint4*)&P[row * 136 + c] = *(const uint4*)(Wub + (size_t)(n0 + row) * D + c);
        }
        __syncthreads();
        #pragma unroll
        for (int rg = 0; rg < 2; ++rg) {
            floatx4 acc[4] = {{0,0,0,0},{0,0,0,0},{0,0,0,0},{0,0,0,0}};
            #pragma unroll
            for (int k0 = 0; k0 < D; k0 += 32) {
                short8 af = *(const short8*)&Af[rg * 64 + w * 16 + mrow][k0 + quad * 8];
                #pragma unroll
                for (int t = 0; t < 4; ++t) {
                    short8 bfr = *(const short8*)&P[(t * 16 + mrow) * 136 + k0 + quad * 8];
                    acc[t] = __builtin_amdgcn_mfma_f32_16x16x32_bf16(af, bfr, acc[t], 0, 0, 0);
                }
            }
            int growb = rowBase + rg * 64 + w * 16 + quad * 4;
            if (growb < M) {
                #pragma unroll
                for (int t = 0; t < 4; ++t) {
                    float bb = bu[n0 + t * 16 + mrow];
                    #pragma unroll
                    for (int r = 0; r < 4; ++r)
                        uout[(size_t)(growb + r) * D + n0 + t * 16 + mrow] =
                            f2bf(acc[t][r] + bb);
                }
            }
        }
    }

    // ---- interleaved phase A/B over 64-col m1 chunks ----
    floatx4 acc2[2][8] = {};
    for (int kc = 0; kc < 4; ++kc) {
        __syncthreads();
        #pragma unroll
        for (int r = 0; r < 4; ++r) {
            int idx = tid + r * 256;
            int row = idx >> 4;
            int c   = (idx & 15) << 3;
            *(uint4*)&P[row * 136 + c] = *(const uint4*)(W1b + (size_t)(kc * 64 + row) * D + c);
        }
        __syncthreads();
        #pragma unroll
        for (int rg = 0; rg < 2; ++rg) {
            floatx4 acc1[4] = {{0,0,0,0},{0,0,0,0},{0,0,0,0},{0,0,0,0}};
            #pragma unroll
            for (int k0 = 0; k0 < D; k0 += 32) {
                short8 af = *(const short8*)&Af[rg * 64 + w * 16 + mrow][k0 + quad * 8];
                #pragma unroll
                for (int t = 0; t < 4; ++t) {
                    short8 bfr = *(const short8*)&P[(t * 16 + mrow) * 136 + k0 + quad * 8];
                    acc1[t] = __builtin_amdgcn_mfma_f32_16x16x32_bf16(af, bfr, acc1[t], 0, 0, 0);
                }
            }
            #pragma unroll
            for (int t = 0; t < 4; ++t) {
                float bb = b1[kc * 64 + t * 16 + mrow];
                #pragma unroll
                for (int r = 0; r < 4; ++r)
                    m1c[rg * 64 + w * 16 + quad * 4 + r][t * 16 + mrow] =
                        f2bf(fmaxf(acc1[t][r] + bb, 0.f));
            }
        }
        __syncthreads();   // all waves done reading W1 panel + m1c written
        #pragma unroll
        for (int r = 0; r < 4; ++r) {
            int idx = tid + r * 256;      // 0..1023
            int row = idx >> 3;           // 0..127
            int c8  = (idx & 7) << 3;     // 0..56
            *(uint4*)&P[row * 72 + c8] = *(const uint4*)(W2b + (size_t)row * H + kc * 64 + c8);
        }
        __syncthreads();
        #pragma unroll
        for (int rg = 0; rg < 2; ++rg) {
            #pragma unroll
            for (int k0 = 0; k0 < 64; k0 += 32) {
                short8 af = *(const short8*)&m1c[rg * 64 + w * 16 + mrow][k0 + quad * 8];
                #pragma unroll
                for (int t2 = 0; t2 < 8; ++t2) {
                    short8 bfr = *(const short8*)&P[(t2 * 16 + mrow) * 72 + k0 + quad * 8];
                    acc2[rg][t2] = __builtin_amdgcn_mfma_f32_16x16x32_bf16(af, bfr, acc2[rg][t2], 0, 0, 0);
                }
            }
        }
    }

    // ---- m2 epilogue: direct C-layout stores (no barriers, no transpose) ----
    #pragma unroll
    for (int rg = 0; rg < 2; ++rg) {
        int growb = rowBase + rg * 64 + w * 16 + quad * 4;
        if (growb < M) {
            #pragma unroll
            for (int t2 = 0; t2 < 8; ++t2) {
                float bb = b2[t2 * 16 + mrow];
                #pragma unroll
                for (int r = 0; r < 4; ++r)
                    m2out[(size_t)(growb + r) * D + t2 * 16 + mrow] =
                        f2bf(fmaxf(acc2[rg][t2][r] + bb, 0.f));
            }
        }
    }
}

// ---------------------------------------------------------------- launch
extern "C" void kernel_launch(void* const* d_in, const int* in_sizes, int n_in,
                              void* d_out, int out_size, void* d_ws, size_t ws_size,
                              hipStream_t stream) {
    const float* x     = (const float*)d_in[0];
    const int*   v_idx = (const int*)d_in[1];
    const int*   e_idx = (const int*)d_in[2];
    const float* W1    = (const float*)d_in[3];
    const float* b1    = (const float*)d_in[4];
    const float* W2    = (const float*)d_in[5];
    const float* b2    = (const float*)d_in[6];
    const float* Wu    = (const float*)d_in[7];
    const float* bu    = (const float*)d_in[8];
    const float* Wa    = (const float*)d_in[9];
    const float* ba    = (const float*)d_in[10];
    float* out = (float*)d_out;

    char* wsp = (char*)d_ws;
    auto alloc = [&](size_t bytes) -> char* {
        char* p = wsp;
        wsp += (bytes + 255) & ~(size_t)255;
        return p;
    };

    ushort* hA     = (ushort*)alloc((size_t)N_NODES * D * 2);
    ushort* m2b    = (ushort*)alloc((size_t)N_NODES * D * 2);
    ushort* ub     = (ushort*)alloc((size_t)N_NODES * D * 2);
    ushort* e_feat = (ushort*)alloc((size_t)N_EDGES * D * 2);
    ushort* W1b    = (ushort*)alloc((size_t)H * D * 2);
    ushort* W2b    = (ushort*)alloc((size_t)D * H * 2);
    ushort* Wub    = (ushort*)alloc((size_t)D * D * 2);
    int*    e_vert = (int*)alloc((size_t)NBE * CAPE * 4);
    int*    v_edge = (int*)alloc((size_t)NBV * CAPV * 4);
    int2*   recE   = (int2*)alloc((size_t)NBE * CAPE * 8);
    int2*   recV   = (int2*)alloc((size_t)NBV * CAPV * 8);
    int*    cntE   = (int*)alloc((size_t)(NBE + NBV) * 4);   // one memset covers both
    int*    cntV   = cntE + NBE;
    int2*   e_sd   = (int2*)alloc((size_t)N_EDGES * 8);
    int2*   v_sd   = (int2*)alloc((size_t)N_NODES * 8);
    float*  erecip = (float*)alloc((size_t)N_EDGES * 4);
    float*  vrecip = (float*)alloc((size_t)N_NODES * 4);

    const int cooBlocks  = (NNZ + CHUNK - 1) / CHUNK;   // 147
    const int convTotal  = H * D / 4 + D * H / 4 + D * D / 4;
    const int convBlocks = (convTotal + 255) / 256;     // 80

    hipMemsetAsync(cntE, 0, (size_t)(NBE + NBV) * 4, stream);
    convert_and_place<<<convBlocks + cooBlocks, 256, 0, stream>>>(
        W1, W1b, W2, W2b, Wu, Wub, v_idx, e_idx, cntE, cntV, recE, recV, convBlocks);
    bucket_final<<<NBE + NBV, 256, 0, stream>>>(recE, cntE, recV, cntV,
                                                e_sd, erecip, e_vert,
                                                v_sd, vrecip, v_edge);

    const int gridM = (N_NODES + 127) / 128;            // 391
    const int gEdge = (N_EDGES * 16 + 255) / 256;       // 1563
    const int gVert = (N_NODES * 16 + 255) / 256;       // 3125

    const void* h = x;
    int h_fp32 = 1;
    for (int depth = 0; depth < 2; ++depth) {
        mlp_fused<<<gridM, 256, 0, stream>>>(h, h_fp32, W1b, b1, W2b, b2, Wub, bu,
                                             m2b, ub, N_NODES);
        // e_feat[e] = erecip[e] * sum m2[v in e]
        gather_rows<<<gEdge, 256, 0, stream>>>(
            m2b, e_sd, e_vert, erecip, nullptr, e_feat, nullptr, nullptr, nullptr, N_EDGES);
        if (depth == 0) {
            // h1[v] = relu(u[v] + vrecip[v] * sum e_feat[e in v])
            gather_rows<<<gVert, 256, 0, stream>>>(
                e_feat, v_sd, v_edge, vrecip, ub, hA, nullptr, nullptr, nullptr, N_NODES);
            h = hA;
            h_fp32 = 0;
        } else {
            // final: fused head -> out = log_softmax(relu(u+agg) @ Wa^T + ba)
            gather_rows<<<gVert, 256, 0, stream>>>(
                e_feat, v_sd, v_edge, vrecip, ub, nullptr, Wa, ba, out, N_NODES);
        }
    }
}